// Round 1
// baseline (208.396 us; speedup 1.0000x reference)
//
#include <hip/hip_runtime.h>
#include <math.h>

#define D 256
#define S 512
#define NB 4
#define M 2048  // NB * S

// ---------------------------------------------------------------------------
// Kernel 1: fused GEMM  out[m, 0:768] = x[m, :] @ [Wa+Wc | Wb-Wc | Wv]
//   region 0 -> hi (+b1), region 1 -> hj, region 2 -> vals (+bv)
// Tile: 64x64, BK=16, 256 threads, 4x4 micro-tile per thread.
// ---------------------------------------------------------------------------
__global__ __launch_bounds__(256) void gemm_qkv(
    const float* __restrict__ x, const float* __restrict__ W1,
    const float* __restrict__ b1, const float* __restrict__ Wv,
    const float* __restrict__ bv, float* __restrict__ hi,
    float* __restrict__ hj, float* __restrict__ vals)
{
    const int bn = blockIdx.x;        // 0..11  (N=768)
    const int bm = blockIdx.y;        // 0..31  (M=2048)
    const int n0 = bn * 64;
    const int region = n0 >> 8;       // 0,1,2 (64 | 256 so block stays in one region)
    const int c0 = n0 & 255;
    const int m0 = bm * 64;
    const int tid = threadIdx.x;

    __shared__ __align__(16) float As[16][64];  // K-major: As[k][m]
    __shared__ __align__(16) float Bs[16][64];  // Bs[k][n]

    const int ar = tid >> 2, ac = (tid & 3) * 4;    // A tile load: 64 rows x 16 k
    const int br = tid >> 4, bc = (tid & 15) * 4;   // B tile load: 16 k x 64 n
    const int ty = tid >> 4, tx = tid & 15;

    float acc[4][4] = {};

    for (int k0 = 0; k0 < D; k0 += 16) {
        float4 a4 = *(const float4*)(x + (m0 + ar) * D + k0 + ac);
        float4 b4;
        if (region == 0) {
            float4 wa = *(const float4*)(W1 + (k0 + br) * D + c0 + bc);
            float4 wc = *(const float4*)(W1 + (512 + k0 + br) * D + c0 + bc);
            b4 = make_float4(wa.x + wc.x, wa.y + wc.y, wa.z + wc.z, wa.w + wc.w);
        } else if (region == 1) {
            float4 wb = *(const float4*)(W1 + (256 + k0 + br) * D + c0 + bc);
            float4 wc = *(const float4*)(W1 + (512 + k0 + br) * D + c0 + bc);
            b4 = make_float4(wb.x - wc.x, wb.y - wc.y, wb.z - wc.z, wb.w - wc.w);
        } else {
            b4 = *(const float4*)(Wv + (k0 + br) * D + c0 + bc);
        }
        __syncthreads();   // protect previous iteration's LDS reads
        As[ac + 0][ar] = a4.x;
        As[ac + 1][ar] = a4.y;
        As[ac + 2][ar] = a4.z;
        As[ac + 3][ar] = a4.w;
        *(float4*)&Bs[br][bc] = b4;
        __syncthreads();
#pragma unroll
        for (int k = 0; k < 16; ++k) {
            float4 av = *(const float4*)&As[k][ty * 4];
            float4 bw = *(const float4*)&Bs[k][tx * 4];
            acc[0][0] += av.x * bw.x; acc[0][1] += av.x * bw.y;
            acc[0][2] += av.x * bw.z; acc[0][3] += av.x * bw.w;
            acc[1][0] += av.y * bw.x; acc[1][1] += av.y * bw.y;
            acc[1][2] += av.y * bw.z; acc[1][3] += av.y * bw.w;
            acc[2][0] += av.z * bw.x; acc[2][1] += av.z * bw.y;
            acc[2][2] += av.z * bw.z; acc[2][3] += av.z * bw.w;
            acc[3][0] += av.w * bw.x; acc[3][1] += av.w * bw.y;
            acc[3][2] += av.w * bw.z; acc[3][3] += av.w * bw.w;
        }
    }

    float4 bias4 = make_float4(0.f, 0.f, 0.f, 0.f);
    if (region == 0) bias4 = *(const float4*)(b1 + c0 + tx * 4);
    else if (region == 2) bias4 = *(const float4*)(bv + c0 + tx * 4);
    float* obase = (region == 0) ? hi : (region == 1) ? hj : vals;
#pragma unroll
    for (int r = 0; r < 4; ++r) {
        const int m = m0 + ty * 4 + r;
        float4 o = make_float4(acc[r][0] + bias4.x, acc[r][1] + bias4.y,
                               acc[r][2] + bias4.z, acc[r][3] + bias4.w);
        *(float4*)(obase + m * D + c0 + tx * 4) = o;
    }
}

// ---------------------------------------------------------------------------
// Kernel 2: per-row fused scores -> softmax -> message
//   one block (256 thr = 4 waves) per row (b,i).  j < i strictly (tril k=-1).
// ---------------------------------------------------------------------------
__global__ __launch_bounds__(256) void attn_kernel(
    const float* __restrict__ hi, const float* __restrict__ hj,
    const float* __restrict__ vals, const float* __restrict__ w2,
    const float* __restrict__ b2, float* __restrict__ msg)
{
    const int row = blockIdx.x;          // 0..2047
    const int b = row >> 9, i = row & 511;
    const int t = threadIdx.x, wave = t >> 6, lane = t & 63;

    if (i == 0) {                        // no valid j: attn row zeroed
        msg[row * D + t] = 0.f;
        return;
    }

    __shared__ float sc[S];
    __shared__ float red[8];

    // phase 1: scores.  each wave covers full h (lane*4 .. lane*4+3), j round-robin
    const float* hirow = hi + row * D;
    float4 hi4 = *(const float4*)(hirow + lane * 4);
    float4 w24 = *(const float4*)(w2 + lane * 4);
    const float b2v = b2[0];
    const float* hjb = hj + (b << 9) * D;
    for (int j = wave; j < i; j += 4) {
        float4 h4 = *(const float4*)(hjb + j * D + lane * 4);
        float p = fmaxf(hi4.x + h4.x, 0.f) * w24.x
                + fmaxf(hi4.y + h4.y, 0.f) * w24.y
                + fmaxf(hi4.z + h4.z, 0.f) * w24.z
                + fmaxf(hi4.w + h4.w, 0.f) * w24.w;
#pragma unroll
        for (int off = 32; off; off >>= 1) p += __shfl_xor(p, off, 64);
        if (lane == 0) sc[j] = p + b2v;
    }
    __syncthreads();

    // phase 2: softmax (block reduce max then sum)
    float mloc = -3.0e38f;
    for (int j = t; j < i; j += 256) mloc = fmaxf(mloc, sc[j]);
#pragma unroll
    for (int off = 32; off; off >>= 1) mloc = fmaxf(mloc, __shfl_xor(mloc, off, 64));
    if (lane == 0) red[wave] = mloc;
    __syncthreads();
    const float mx = fmaxf(fmaxf(red[0], red[1]), fmaxf(red[2], red[3]));

    float sloc = 0.f;
    for (int j = t; j < i; j += 256) {
        float e = __expf(sc[j] - mx);
        sc[j] = e;
        sloc += e;
    }
#pragma unroll
    for (int off = 32; off; off >>= 1) sloc += __shfl_xor(sloc, off, 64);
    if (lane == 0) red[4 + wave] = sloc;
    __syncthreads();
    const float inv = 1.f / (red[4] + red[5] + red[6] + red[7]);

    // phase 3: message[t] = (1/sum) * sum_j e_j * vals[b, j, t]
    const float* vb = vals + (b << 9) * D + t;
    float acc = 0.f;
    int j = 0;
    for (; j + 4 <= i; j += 4) {
        acc += sc[j]     * vb[(j)     * D];
        acc += sc[j + 1] * vb[(j + 1) * D];
        acc += sc[j + 2] * vb[(j + 2) * D];
        acc += sc[j + 3] * vb[(j + 3) * D];
    }
    for (; j < i; ++j) acc += sc[j] * vb[j * D];
    msg[row * D + t] = acc * inv;
}

// ---------------------------------------------------------------------------
// Kernel 3: out = LayerNorm(x + msg @ Wo + bo) * gamma + beta
//   one block per row; thread t owns output column t.
// ---------------------------------------------------------------------------
__global__ __launch_bounds__(256) void out_kernel(
    const float* __restrict__ x, const float* __restrict__ msg,
    const float* __restrict__ Wo, const float* __restrict__ bo,
    const float* __restrict__ gamma, const float* __restrict__ beta,
    float* __restrict__ out)
{
    const int row = blockIdx.x, t = threadIdx.x;
    const int wave = t >> 6, lane = t & 63;
    __shared__ float ms[D];
    __shared__ float red[8];

    ms[t] = msg[row * D + t];
    __syncthreads();

    float acc = 0.f;
#pragma unroll 4
    for (int d = 0; d < D; ++d) acc += ms[d] * Wo[d * D + t];

    float v = x[row * D + t] + acc + bo[t];

    // mean
    float sm = v;
#pragma unroll
    for (int off = 32; off; off >>= 1) sm += __shfl_xor(sm, off, 64);
    if (lane == 0) red[wave] = sm;
    __syncthreads();
    const float mu = (red[0] + red[1] + red[2] + red[3]) * (1.f / D);

    // var
    const float dfr = v - mu;
    float sq = dfr * dfr;
#pragma unroll
    for (int off = 32; off; off >>= 1) sq += __shfl_xor(sq, off, 64);
    if (lane == 0) red[4 + wave] = sq;
    __syncthreads();
    const float var = (red[4] + red[5] + red[6] + red[7]) * (1.f / D);

    out[row * D + t] = dfr * rsqrtf(var + 1e-5f) * gamma[t] + beta[t];
}

// ---------------------------------------------------------------------------
extern "C" void kernel_launch(void* const* d_in, const int* in_sizes, int n_in,
                              void* d_out, int out_size, void* d_ws, size_t ws_size,
                              hipStream_t stream)
{
    (void)in_sizes; (void)n_in; (void)out_size; (void)ws_size;
    const float* x     = (const float*)d_in[0];
    const float* W1    = (const float*)d_in[1];
    const float* b1    = (const float*)d_in[2];
    const float* w2    = (const float*)d_in[3];
    const float* b2    = (const float*)d_in[4];
    const float* Wv    = (const float*)d_in[5];
    const float* bv    = (const float*)d_in[6];
    const float* Wo    = (const float*)d_in[7];
    const float* bo    = (const float*)d_in[8];
    const float* gamma = (const float*)d_in[9];
    const float* beta  = (const float*)d_in[10];
    float* out = (float*)d_out;

    float* ws   = (float*)d_ws;
    float* hi   = ws;               // 2048*256 fp32 (= 2 MB)
    float* hj   = ws + (size_t)M * D;
    float* vals = ws + (size_t)2 * M * D;
    float* msg  = ws + (size_t)3 * M * D;

    gemm_qkv<<<dim3(12, 32), 256, 0, stream>>>(x, W1, b1, Wv, bv, hi, hj, vals);
    attn_kernel<<<dim3(M), 256, 0, stream>>>(hi, hj, vals, w2, b2, msg);
    out_kernel<<<dim3(M), 256, 0, stream>>>(x, msg, Wo, bo, gamma, beta, out);
}

// Round 2
// 184.109 us; speedup vs baseline: 1.1319x; 1.1319x over previous
//
#include <hip/hip_runtime.h>
#include <math.h>

#define D 256
#define S 512
#define M 2048  // 4 * 512

// ---------------------------------------------------------------------------
// Kernel 1: fused GEMM  [hi | hj | vals] = x @ [Wa+Wc | Wb-Wc | Wv] (+biases)
// 64x64 tile, BK=16, 256 threads, 4x4 micro-tile. (unchanged from R1)
// ---------------------------------------------------------------------------
__global__ __launch_bounds__(256) void gemm_qkv(
    const float* __restrict__ x, const float* __restrict__ W1,
    const float* __restrict__ b1, const float* __restrict__ Wv,
    const float* __restrict__ bv, float* __restrict__ hi,
    float* __restrict__ hj, float* __restrict__ vals)
{
    const int bn = blockIdx.x;
    const int bm = blockIdx.y;
    const int n0 = bn * 64;
    const int region = n0 >> 8;
    const int c0 = n0 & 255;
    const int m0 = bm * 64;
    const int tid = threadIdx.x;

    __shared__ __align__(16) float As[16][64];
    __shared__ __align__(16) float Bs[16][64];

    const int ar = tid >> 2, ac = (tid & 3) * 4;
    const int br = tid >> 4, bc = (tid & 15) * 4;
    const int ty = tid >> 4, tx = tid & 15;

    float acc[4][4] = {};

    for (int k0 = 0; k0 < D; k0 += 16) {
        float4 a4 = *(const float4*)(x + (m0 + ar) * D + k0 + ac);
        float4 b4;
        if (region == 0) {
            float4 wa = *(const float4*)(W1 + (k0 + br) * D + c0 + bc);
            float4 wc = *(const float4*)(W1 + (512 + k0 + br) * D + c0 + bc);
            b4 = make_float4(wa.x + wc.x, wa.y + wc.y, wa.z + wc.z, wa.w + wc.w);
        } else if (region == 1) {
            float4 wb = *(const float4*)(W1 + (256 + k0 + br) * D + c0 + bc);
            float4 wc = *(const float4*)(W1 + (512 + k0 + br) * D + c0 + bc);
            b4 = make_float4(wb.x - wc.x, wb.y - wc.y, wb.z - wc.z, wb.w - wc.w);
        } else {
            b4 = *(const float4*)(Wv + (k0 + br) * D + c0 + bc);
        }
        __syncthreads();
        As[ac + 0][ar] = a4.x;
        As[ac + 1][ar] = a4.y;
        As[ac + 2][ar] = a4.z;
        As[ac + 3][ar] = a4.w;
        *(float4*)&Bs[br][bc] = b4;
        __syncthreads();
#pragma unroll
        for (int k = 0; k < 16; ++k) {
            float4 av = *(const float4*)&As[k][ty * 4];
            float4 bw = *(const float4*)&Bs[k][tx * 4];
            acc[0][0] += av.x * bw.x; acc[0][1] += av.x * bw.y;
            acc[0][2] += av.x * bw.z; acc[0][3] += av.x * bw.w;
            acc[1][0] += av.y * bw.x; acc[1][1] += av.y * bw.y;
            acc[1][2] += av.y * bw.z; acc[1][3] += av.y * bw.w;
            acc[2][0] += av.z * bw.x; acc[2][1] += av.z * bw.y;
            acc[2][2] += av.z * bw.z; acc[2][3] += av.z * bw.w;
            acc[3][0] += av.w * bw.x; acc[3][1] += av.w * bw.y;
            acc[3][2] += av.w * bw.z; acc[3][3] += av.w * bw.w;
        }
    }

    float4 bias4 = make_float4(0.f, 0.f, 0.f, 0.f);
    if (region == 0) bias4 = *(const float4*)(b1 + c0 + tx * 4);
    else if (region == 2) bias4 = *(const float4*)(bv + c0 + tx * 4);
    float* obase = (region == 0) ? hi : (region == 1) ? hj : vals;
#pragma unroll
    for (int r = 0; r < 4; ++r) {
        const int m = m0 + ty * 4 + r;
        float4 o = make_float4(acc[r][0] + bias4.x, acc[r][1] + bias4.y,
                               acc[r][2] + bias4.z, acc[r][3] + bias4.w);
        *(float4*)(obase + m * D + c0 + tx * 4) = o;
    }
}

// ---------------------------------------------------------------------------
// Kernel 2: tiled scores.  Tile = 32 i x 32 j, thread owns 2x2 pairs.
// LDS layout h-interleaved: His[h2][2*r + p] holds hi[i0+r][hc + 2*h2 + p],
// so one ds_read_b128 delivers 2 i's x 2 h's.  Writes raw scores (+b2).
// Only tiles jt <= it launched (strict lower triangle coverage).
// ---------------------------------------------------------------------------
__global__ __launch_bounds__(256) void scores_tiled(
    const float* __restrict__ hi, const float* __restrict__ hj,
    const float* __restrict__ w2, const float* __restrict__ b2,
    float* __restrict__ sc)
{
    const int jt = blockIdx.x, it = blockIdx.y, b = blockIdx.z;
    if (jt > it) return;
    const int i0 = it * 32, j0 = jt * 32;
    const int t = threadIdx.x;

    __shared__ __align__(16) float His[32][64];
    __shared__ __align__(16) float Hjs[32][64];
    __shared__ __align__(16) float w2s[256];

    if (t < 64) {
        *(float4*)&w2s[t * 4] = *(const float4*)(w2 + t * 4);
    }

    const int r = t & 31;                 // staging: lane-per-row
    const int cbase = (t >> 5) * 4;       // h-offset group
    const float* hirow = hi + ((b << 9) + i0 + r) * D;
    const float* hjrow = hj + ((b << 9) + j0 + r) * D;

    const int ti4 = (t & 15) * 4;         // compute: i-pair column base
    const int tj4 = (t >> 4) * 4;         // j-pair column base

    float acc00 = 0.f, acc01 = 0.f, acc10 = 0.f, acc11 = 0.f;

    for (int hc = 0; hc < 256; hc += 64) {
        const int c4a = cbase, c4b = cbase + 32;
        float4 a0 = *(const float4*)(hirow + hc + c4a);
        float4 a1 = *(const float4*)(hirow + hc + c4b);
        float4 e0 = *(const float4*)(hjrow + hc + c4a);
        float4 e1 = *(const float4*)(hjrow + hc + c4b);
        __syncthreads();   // protect previous chunk's LDS reads
        *(float2*)&His[(c4a >> 1) + 0][2 * r] = make_float2(a0.x, a0.y);
        *(float2*)&His[(c4a >> 1) + 1][2 * r] = make_float2(a0.z, a0.w);
        *(float2*)&His[(c4b >> 1) + 0][2 * r] = make_float2(a1.x, a1.y);
        *(float2*)&His[(c4b >> 1) + 1][2 * r] = make_float2(a1.z, a1.w);
        *(float2*)&Hjs[(c4a >> 1) + 0][2 * r] = make_float2(e0.x, e0.y);
        *(float2*)&Hjs[(c4a >> 1) + 1][2 * r] = make_float2(e0.z, e0.w);
        *(float2*)&Hjs[(c4b >> 1) + 0][2 * r] = make_float2(e1.x, e1.y);
        *(float2*)&Hjs[(c4b >> 1) + 1][2 * r] = make_float2(e1.z, e1.w);
        __syncthreads();
#pragma unroll 8
        for (int h2 = 0; h2 < 32; ++h2) {
            float4 a = *(const float4*)&His[h2][ti4];
            float4 e = *(const float4*)&Hjs[h2][tj4];
            float2 w = *(const float2*)&w2s[hc + h2 * 2];
            acc00 += fmaxf(a.x + e.x, 0.f) * w.x + fmaxf(a.y + e.y, 0.f) * w.y;
            acc01 += fmaxf(a.x + e.z, 0.f) * w.x + fmaxf(a.y + e.w, 0.f) * w.y;
            acc10 += fmaxf(a.z + e.x, 0.f) * w.x + fmaxf(a.w + e.y, 0.f) * w.y;
            acc11 += fmaxf(a.z + e.z, 0.f) * w.x + fmaxf(a.w + e.w, 0.f) * w.y;
        }
    }

    const float b2v = b2[0];
    float* srow = sc + ((size_t)b << 18) + (size_t)(i0 + ((t & 15) << 1)) * S
                + j0 + ((t >> 4) << 1);
    srow[0] = acc00 + b2v;
    srow[1] = acc01 + b2v;
    srow[S] = acc10 + b2v;
    srow[S + 1] = acc11 + b2v;
}

// ---------------------------------------------------------------------------
// Kernel 3: per-row softmax over j<i, zero-fill j>=i (and all of row 0).
// Produces a clean attn matrix in-place so PV is a plain GEMM.
// ---------------------------------------------------------------------------
__global__ __launch_bounds__(256) void attn_norm(float* __restrict__ sc)
{
    const int row = blockIdx.x;
    const int b = row >> 9, i = row & 511;
    const int t = threadIdx.x, wave = t >> 6, lane = t & 63;
    float* srow = sc + ((size_t)b << 18) + (size_t)i * S;

    if (i == 0) {
        srow[t] = 0.f;
        srow[t + 256] = 0.f;
        return;
    }

    __shared__ float red[8];

    float mloc = -3.0e38f;
    for (int j = t; j < i; j += 256) mloc = fmaxf(mloc, srow[j]);
#pragma unroll
    for (int off = 32; off; off >>= 1) mloc = fmaxf(mloc, __shfl_xor(mloc, off, 64));
    if (lane == 0) red[wave] = mloc;
    __syncthreads();
    const float mx = fmaxf(fmaxf(red[0], red[1]), fmaxf(red[2], red[3]));

    float sloc = 0.f;
    for (int j = t; j < i; j += 256) {
        float e = __expf(srow[j] - mx);
        srow[j] = e;
        sloc += e;
    }
#pragma unroll
    for (int off = 32; off; off >>= 1) sloc += __shfl_xor(sloc, off, 64);
    if (lane == 0) red[4 + wave] = sloc;
    __syncthreads();
    const float inv = 1.f / (red[4] + red[5] + red[6] + red[7]);

    for (int j = t; j < 512; j += 256)
        srow[j] = (j < i) ? srow[j] * inv : 0.f;
}

// ---------------------------------------------------------------------------
// Kernel 4: msg = attn @ vals  (per batch).  64x64 tile, K truncated at
// i0+64 (attn is zero beyond the causal boundary).
// ---------------------------------------------------------------------------
__global__ __launch_bounds__(256) void pv_gemm(
    const float* __restrict__ attn, const float* __restrict__ vals,
    float* __restrict__ msg)
{
    const int bn = blockIdx.x, bm = blockIdx.y, b = blockIdx.z;
    const int n0 = bn * 64, m0 = bm * 64;
    const int tid = threadIdx.x;
    const float* A = attn + ((size_t)b << 18);
    const float* B = vals + (size_t)(b << 9) * D;

    __shared__ __align__(16) float As[16][64];
    __shared__ __align__(16) float Bs[16][64];

    const int ar = tid >> 2, ac = (tid & 3) * 4;
    const int br = tid >> 4, bc = (tid & 15) * 4;
    const int ty = tid >> 4, tx = tid & 15;
    float acc[4][4] = {};

    const int kmax = m0 + 64;   // causal: attn[i][j]=0 for j >= i
    for (int k0 = 0; k0 < kmax; k0 += 16) {
        float4 a4 = *(const float4*)(A + (size_t)(m0 + ar) * S + k0 + ac);
        float4 b4 = *(const float4*)(B + (k0 + br) * D + n0 + bc);
        __syncthreads();
        As[ac + 0][ar] = a4.x;
        As[ac + 1][ar] = a4.y;
        As[ac + 2][ar] = a4.z;
        As[ac + 3][ar] = a4.w;
        *(float4*)&Bs[br][bc] = b4;
        __syncthreads();
#pragma unroll
        for (int k = 0; k < 16; ++k) {
            float4 av = *(const float4*)&As[k][ty * 4];
            float4 bw = *(const float4*)&Bs[k][tx * 4];
            acc[0][0] += av.x * bw.x; acc[0][1] += av.x * bw.y;
            acc[0][2] += av.x * bw.z; acc[0][3] += av.x * bw.w;
            acc[1][0] += av.y * bw.x; acc[1][1] += av.y * bw.y;
            acc[1][2] += av.y * bw.z; acc[1][3] += av.y * bw.w;
            acc[2][0] += av.z * bw.x; acc[2][1] += av.z * bw.y;
            acc[2][2] += av.z * bw.z; acc[2][3] += av.z * bw.w;
            acc[3][0] += av.w * bw.x; acc[3][1] += av.w * bw.y;
            acc[3][2] += av.w * bw.z; acc[3][3] += av.w * bw.w;
        }
    }
#pragma unroll
    for (int r = 0; r < 4; ++r) {
        const int m = m0 + ty * 4 + r;
        *(float4*)(msg + (size_t)((b << 9) + m) * D + n0 + tx * 4) =
            make_float4(acc[r][0], acc[r][1], acc[r][2], acc[r][3]);
    }
}

// ---------------------------------------------------------------------------
// Kernel 5: tmp = x + msg @ Wo + bo.  64x64 tile over (M=2048, N=256), K=256.
// ---------------------------------------------------------------------------
__global__ __launch_bounds__(256) void gemm_out(
    const float* __restrict__ msg, const float* __restrict__ Wo,
    const float* __restrict__ x, const float* __restrict__ bo,
    float* __restrict__ tmp)
{
    const int bn = blockIdx.x, bm = blockIdx.y;
    const int n0 = bn * 64, m0 = bm * 64;
    const int tid = threadIdx.x;

    __shared__ __align__(16) float As[16][64];
    __shared__ __align__(16) float Bs[16][64];

    const int ar = tid >> 2, ac = (tid & 3) * 4;
    const int br = tid >> 4, bc = (tid & 15) * 4;
    const int ty = tid >> 4, tx = tid & 15;
    float acc[4][4] = {};

    for (int k0 = 0; k0 < D; k0 += 16) {
        float4 a4 = *(const float4*)(msg + (size_t)(m0 + ar) * D + k0 + ac);
        float4 b4 = *(const float4*)(Wo + (k0 + br) * D + n0 + bc);
        __syncthreads();
        As[ac + 0][ar] = a4.x;
        As[ac + 1][ar] = a4.y;
        As[ac + 2][ar] = a4.z;
        As[ac + 3][ar] = a4.w;
        *(float4*)&Bs[br][bc] = b4;
        __syncthreads();
#pragma unroll
        for (int k = 0; k < 16; ++k) {
            float4 av = *(const float4*)&As[k][ty * 4];
            float4 bw = *(const float4*)&Bs[k][tx * 4];
            acc[0][0] += av.x * bw.x; acc[0][1] += av.x * bw.y;
            acc[0][2] += av.x * bw.z; acc[0][3] += av.x * bw.w;
            acc[1][0] += av.y * bw.x; acc[1][1] += av.y * bw.y;
            acc[1][2] += av.y * bw.z; acc[1][3] += av.y * bw.w;
            acc[2][0] += av.z * bw.x; acc[2][1] += av.z * bw.y;
            acc[2][2] += av.z * bw.z; acc[2][3] += av.z * bw.w;
            acc[3][0] += av.w * bw.x; acc[3][1] += av.w * bw.y;
            acc[3][2] += av.w * bw.z; acc[3][3] += av.w * bw.w;
        }
    }

    const float4 bo4 = *(const float4*)(bo + n0 + tx * 4);
#pragma unroll
    for (int r = 0; r < 4; ++r) {
        const int m = m0 + ty * 4 + r;
        float4 xv = *(const float4*)(x + (size_t)m * D + n0 + tx * 4);
        *(float4*)(tmp + (size_t)m * D + n0 + tx * 4) =
            make_float4(acc[r][0] + xv.x + bo4.x, acc[r][1] + xv.y + bo4.y,
                        acc[r][2] + xv.z + bo4.z, acc[r][3] + xv.w + bo4.w);
    }
}

// ---------------------------------------------------------------------------
// Kernel 6: LayerNorm per row.
// ---------------------------------------------------------------------------
__global__ __launch_bounds__(256) void ln_kernel(
    const float* __restrict__ tmp, const float* __restrict__ gamma,
    const float* __restrict__ beta, float* __restrict__ out)
{
    const int row = blockIdx.x, t = threadIdx.x;
    const int wave = t >> 6, lane = t & 63;
    __shared__ float red[8];

    const float v = tmp[(size_t)row * D + t];

    float sm = v;
#pragma unroll
    for (int off = 32; off; off >>= 1) sm += __shfl_xor(sm, off, 64);
    if (lane == 0) red[wave] = sm;
    __syncthreads();
    const float mu = (red[0] + red[1] + red[2] + red[3]) * (1.f / D);

    const float dfr = v - mu;
    float sq = dfr * dfr;
#pragma unroll
    for (int off = 32; off; off >>= 1) sq += __shfl_xor(sq, off, 64);
    if (lane == 0) red[4 + wave] = sq;
    __syncthreads();
    const float var = (red[4] + red[5] + red[6] + red[7]) * (1.f / D);

    out[(size_t)row * D + t] = dfr * rsqrtf(var + 1e-5f) * gamma[t] + beta[t];
}

// ---------------------------------------------------------------------------
extern "C" void kernel_launch(void* const* d_in, const int* in_sizes, int n_in,
                              void* d_out, int out_size, void* d_ws, size_t ws_size,
                              hipStream_t stream)
{
    (void)in_sizes; (void)n_in; (void)out_size; (void)ws_size;
    const float* x     = (const float*)d_in[0];
    const float* W1    = (const float*)d_in[1];
    const float* b1    = (const float*)d_in[2];
    const float* w2    = (const float*)d_in[3];
    const float* b2    = (const float*)d_in[4];
    const float* Wv    = (const float*)d_in[5];
    const float* bv    = (const float*)d_in[6];
    const float* Wo    = (const float*)d_in[7];
    const float* bo    = (const float*)d_in[8];
    const float* gamma = (const float*)d_in[9];
    const float* beta  = (const float*)d_in[10];
    float* out = (float*)d_out;

    float* ws   = (float*)d_ws;
    float* hi   = ws;                         // 2048*256       (2 MB)
    float* hj   = ws + (size_t)M * D;         // 2048*256       (2 MB)
    float* vals = ws + (size_t)2 * M * D;     // 2048*256       (2 MB)
    float* sc   = ws + (size_t)3 * M * D;     // 4*512*512      (4 MB)
    float* msg  = hi;                         // hi dead after scores_tiled
    float* tmp  = hj;                         // hj dead after scores_tiled

    gemm_qkv    <<<dim3(12, 32),    256, 0, stream>>>(x, W1, b1, Wv, bv, hi, hj, vals);
    scores_tiled<<<dim3(16, 16, 4), 256, 0, stream>>>(hi, hj, w2, b2, sc);
    attn_norm   <<<dim3(M),         256, 0, stream>>>(sc);
    pv_gemm     <<<dim3(4, 8, 4),   256, 0, stream>>>(sc, vals, msg);
    gemm_out    <<<dim3(4, 32),     256, 0, stream>>>(msg, Wo, x, bo, tmp);
    ln_kernel   <<<dim3(M),         256, 0, stream>>>(tmp, gamma, beta, out);
}

// Round 3
// 152.317 us; speedup vs baseline: 1.3682x; 1.2087x over previous
//
#include <hip/hip_runtime.h>
#include <math.h>

#define D 256
#define S 512
#define M 2048  // 4 * 512

typedef __attribute__((ext_vector_type(8))) short bf16x8;
typedef __attribute__((ext_vector_type(4))) float f32x4;

__device__ inline ushort f2bf(float f) {
    union { float f; unsigned u; } v; v.f = f;
    unsigned r = v.u + 0x7FFFu + ((v.u >> 16) & 1u);   // RNE
    return (ushort)(r >> 16);
}

// ---------------------------------------------------------------------------
// Kernel 0: pack.  Blocks 0..63: transpose+convert weights to bf16 [n][k]:
//   WAt[h][d]=Wa+Wc, WBt[h][d]=Wb-Wc, Wvt[e][d]=Wv^T, Wot[e][d]=Wo^T.
// Blocks 64..319: x (f32 row-major) -> xb (bf16 row-major).
// ---------------------------------------------------------------------------
__global__ __launch_bounds__(256) void pack_all(
    const float* __restrict__ x, const float* __restrict__ W1,
    const float* __restrict__ Wv, const float* __restrict__ Wo,
    ushort* __restrict__ xb, ushort* __restrict__ WAt, ushort* __restrict__ WBt,
    ushort* __restrict__ Wvt, ushort* __restrict__ Wot)
{
    const int blk = blockIdx.x, t = threadIdx.x;
    if (blk < 64) {
        const int mat = blk >> 4;
        const int a0 = ((blk >> 2) & 3) * 64;   // dst row block (h/e = src col)
        const int b0 = (blk & 3) * 64;          // dst col block (d = src row)
        __shared__ ushort lt[64][72];
        const int r = t >> 4;                   // 0..15
        const int c = (t & 15) * 4;
#pragma unroll
        for (int p = 0; p < 4; ++p) {
            const int sr = b0 + p * 16 + r;     // src row (d)
            float4 v;
            if (mat == 0) {
                float4 wa = *(const float4*)(W1 + (size_t)sr * 256 + a0 + c);
                float4 wc = *(const float4*)(W1 + (size_t)(512 + sr) * 256 + a0 + c);
                v = make_float4(wa.x + wc.x, wa.y + wc.y, wa.z + wc.z, wa.w + wc.w);
            } else if (mat == 1) {
                float4 wb = *(const float4*)(W1 + (size_t)(256 + sr) * 256 + a0 + c);
                float4 wc = *(const float4*)(W1 + (size_t)(512 + sr) * 256 + a0 + c);
                v = make_float4(wb.x - wc.x, wb.y - wc.y, wb.z - wc.z, wb.w - wc.w);
            } else if (mat == 2) {
                v = *(const float4*)(Wv + (size_t)sr * 256 + a0 + c);
            } else {
                v = *(const float4*)(Wo + (size_t)sr * 256 + a0 + c);
            }
            lt[p * 16 + r][c + 0] = f2bf(v.x);
            lt[p * 16 + r][c + 1] = f2bf(v.y);
            lt[p * 16 + r][c + 2] = f2bf(v.z);
            lt[p * 16 + r][c + 3] = f2bf(v.w);
        }
        __syncthreads();
        ushort* dst = (mat == 0) ? WAt : (mat == 1) ? WBt : (mat == 2) ? Wvt : Wot;
#pragma unroll
        for (int p = 0; p < 4; ++p) {
            const int dr = p * 16 + r;          // dst row within tile (h)
            ushort4 o = make_ushort4(lt[c + 0][dr], lt[c + 1][dr],
                                     lt[c + 2][dr], lt[c + 3][dr]);
            *(ushort4*)(dst + (size_t)(a0 + dr) * 256 + b0 + c) = o;
        }
    } else {
        const int idx = ((blk - 64) * 256 + t) * 8;   // 256 blocks cover 2048*256
        float4 v0 = *(const float4*)(x + idx);
        float4 v1 = *(const float4*)(x + idx + 4);
        *(ushort4*)(xb + idx)     = make_ushort4(f2bf(v0.x), f2bf(v0.y), f2bf(v0.z), f2bf(v0.w));
        *(ushort4*)(xb + idx + 4) = make_ushort4(f2bf(v1.x), f2bf(v1.y), f2bf(v1.z), f2bf(v1.w));
    }
}

// ---------------------------------------------------------------------------
// Kernel 1: MFMA QKV.  [hi | hj | vals] = xb @ [WAt|WBt|Wvt]^T (+biases).
// Block = 4 waves (2x2), wave tile 32x32, block tile 64x64. No LDS.
// hi/hj written fp32 (consumed by VALU scores); vals written bf16.
// ---------------------------------------------------------------------------
__global__ __launch_bounds__(256) void gemm_qkv_mfma(
    const ushort* __restrict__ xb, const ushort* __restrict__ WAt,
    const ushort* __restrict__ WBt, const ushort* __restrict__ Wvt,
    const float* __restrict__ b1, const float* __restrict__ bv,
    float* __restrict__ hi, float* __restrict__ hj, ushort* __restrict__ vals_bf)
{
    const int bn = blockIdx.x, bm = blockIdx.y;
    const int n0 = bn * 64, m0 = bm * 64;
    const int region = n0 >> 8, c0 = n0 & 255;
    const ushort* Bt = (region == 0) ? WAt : (region == 1) ? WBt : Wvt;
    const int t = threadIdx.x, w = t >> 6, l = t & 63;
    const int q = l >> 4, ln = l & 15;
    const int wm = (w >> 1) * 32, wn = (w & 1) * 32;

    f32x4 acc[2][2] = {};
    for (int k0 = 0; k0 < 256; k0 += 32) {
        bf16x8 a[2], b[2];
#pragma unroll
        for (int mt = 0; mt < 2; ++mt)
            a[mt] = *(const bf16x8*)(xb + (size_t)(m0 + wm + mt * 16 + ln) * 256 + k0 + q * 8);
#pragma unroll
        for (int nt = 0; nt < 2; ++nt)
            b[nt] = *(const bf16x8*)(Bt + (size_t)(c0 + wn + nt * 16 + ln) * 256 + k0 + q * 8);
#pragma unroll
        for (int mt = 0; mt < 2; ++mt)
#pragma unroll
            for (int nt = 0; nt < 2; ++nt)
                acc[mt][nt] = __builtin_amdgcn_mfma_f32_16x16x32_bf16(a[mt], b[nt], acc[mt][nt], 0, 0, 0);
    }

    if (region < 2) {
        float* dst = (region == 0) ? hi : hj;
#pragma unroll
        for (int nt = 0; nt < 2; ++nt) {
            const int col = c0 + wn + nt * 16 + ln;
            const float bias = (region == 0) ? b1[col] : 0.f;
#pragma unroll
            for (int mt = 0; mt < 2; ++mt)
#pragma unroll
                for (int r = 0; r < 4; ++r) {
                    const int row = m0 + wm + mt * 16 + q * 4 + r;
                    dst[(size_t)row * 256 + col] = acc[mt][nt][r] + bias;
                }
        }
    } else {
#pragma unroll
        for (int nt = 0; nt < 2; ++nt) {
            const int col = c0 + wn + nt * 16 + ln;
            const float bias = bv[col];
#pragma unroll
            for (int mt = 0; mt < 2; ++mt)
#pragma unroll
                for (int r = 0; r < 4; ++r) {
                    const int row = m0 + wm + mt * 16 + q * 4 + r;
                    vals_bf[(size_t)row * 256 + col] = f2bf(acc[mt][nt][r] + bias);
                }
        }
    }
}

// ---------------------------------------------------------------------------
// Kernel 2: tiled scores (VALU; unchanged from R2 — verified).
// ---------------------------------------------------------------------------
__global__ __launch_bounds__(256) void scores_tiled(
    const float* __restrict__ hi, const float* __restrict__ hj,
    const float* __restrict__ w2, const float* __restrict__ b2,
    float* __restrict__ sc)
{
    const int jt = blockIdx.x, it = blockIdx.y, b = blockIdx.z;
    if (jt > it) return;
    const int i0 = it * 32, j0 = jt * 32;
    const int t = threadIdx.x;

    __shared__ __align__(16) float His[32][64];
    __shared__ __align__(16) float Hjs[32][64];
    __shared__ __align__(16) float w2s[256];

    if (t < 64) *(float4*)&w2s[t * 4] = *(const float4*)(w2 + t * 4);

    const int r = t & 31;
    const int cbase = (t >> 5) * 4;
    const float* hirow = hi + ((b << 9) + i0 + r) * D;
    const float* hjrow = hj + ((b << 9) + j0 + r) * D;

    const int ti4 = (t & 15) * 4;
    const int tj4 = (t >> 4) * 4;

    float acc00 = 0.f, acc01 = 0.f, acc10 = 0.f, acc11 = 0.f;

    for (int hc = 0; hc < 256; hc += 64) {
        const int c4a = cbase, c4b = cbase + 32;
        float4 a0 = *(const float4*)(hirow + hc + c4a);
        float4 a1 = *(const float4*)(hirow + hc + c4b);
        float4 e0 = *(const float4*)(hjrow + hc + c4a);
        float4 e1 = *(const float4*)(hjrow + hc + c4b);
        __syncthreads();
        *(float2*)&His[(c4a >> 1) + 0][2 * r] = make_float2(a0.x, a0.y);
        *(float2*)&His[(c4a >> 1) + 1][2 * r] = make_float2(a0.z, a0.w);
        *(float2*)&His[(c4b >> 1) + 0][2 * r] = make_float2(a1.x, a1.y);
        *(float2*)&His[(c4b >> 1) + 1][2 * r] = make_float2(a1.z, a1.w);
        *(float2*)&Hjs[(c4a >> 1) + 0][2 * r] = make_float2(e0.x, e0.y);
        *(float2*)&Hjs[(c4a >> 1) + 1][2 * r] = make_float2(e0.z, e0.w);
        *(float2*)&Hjs[(c4b >> 1) + 0][2 * r] = make_float2(e1.x, e1.y);
        *(float2*)&Hjs[(c4b >> 1) + 1][2 * r] = make_float2(e1.z, e1.w);
        __syncthreads();
#pragma unroll 8
        for (int h2 = 0; h2 < 32; ++h2) {
            float4 a = *(const float4*)&His[h2][ti4];
            float4 e = *(const float4*)&Hjs[h2][tj4];
            float2 w = *(const float2*)&w2s[hc + h2 * 2];
            acc00 += fmaxf(a.x + e.x, 0.f) * w.x + fmaxf(a.y + e.y, 0.f) * w.y;
            acc01 += fmaxf(a.x + e.z, 0.f) * w.x + fmaxf(a.y + e.w, 0.f) * w.y;
            acc10 += fmaxf(a.z + e.x, 0.f) * w.x + fmaxf(a.w + e.y, 0.f) * w.y;
            acc11 += fmaxf(a.z + e.z, 0.f) * w.x + fmaxf(a.w + e.w, 0.f) * w.y;
        }
    }

    const float b2v = b2[0];
    float* srow = sc + ((size_t)b << 18) + (size_t)(i0 + ((t & 15) << 1)) * S
                + j0 + ((t >> 4) << 1);
    srow[0] = acc00 + b2v;
    srow[1] = acc01 + b2v;
    srow[S] = acc10 + b2v;
    srow[S + 1] = acc11 + b2v;
}

// ---------------------------------------------------------------------------
// Kernel 3: softmax over j<i -> attn_bf (bf16, zero-filled j>=i and row 0).
// ---------------------------------------------------------------------------
__global__ __launch_bounds__(256) void attn_norm(
    const float* __restrict__ sc, ushort* __restrict__ attn_bf)
{
    const int row = blockIdx.x;
    const int b = row >> 9, i = row & 511;
    const int t = threadIdx.x, wave = t >> 6, lane = t & 63;
    ushort* arow = attn_bf + ((size_t)(b << 9) + i) * S;

    if (i == 0) { arow[t] = 0; arow[t + 256] = 0; return; }

    const float* srow = sc + ((size_t)b << 18) + (size_t)i * S;
    __shared__ float s[S];
    __shared__ float red[8];

    float mloc = -3.0e38f;
    for (int j = t; j < i; j += 256) { float v = srow[j]; s[j] = v; mloc = fmaxf(mloc, v); }
#pragma unroll
    for (int off = 32; off; off >>= 1) mloc = fmaxf(mloc, __shfl_xor(mloc, off, 64));
    if (lane == 0) red[wave] = mloc;
    __syncthreads();
    const float mx = fmaxf(fmaxf(red[0], red[1]), fmaxf(red[2], red[3]));

    float sloc = 0.f;
    for (int j = t; j < i; j += 256) {
        float e = __expf(s[j] - mx);
        s[j] = e;
        sloc += e;
    }
#pragma unroll
    for (int off = 32; off; off >>= 1) sloc += __shfl_xor(sloc, off, 64);
    if (lane == 0) red[4 + wave] = sloc;
    __syncthreads();
    const float inv = 1.f / (red[4] + red[5] + red[6] + red[7]);

    for (int j = t; j < S; j += 256)
        arow[j] = (j < i) ? f2bf(s[j] * inv) : (ushort)0;
}

// ---------------------------------------------------------------------------
// Kernel 4: MFMA PV.  msg = attn @ vals (per batch), causal K-truncation.
// A-frags contiguous from attn_bf; B-frags gathered from row-major vals_bf.
// ---------------------------------------------------------------------------
__global__ __launch_bounds__(256) void pv_mfma(
    const ushort* __restrict__ attn_bf, const ushort* __restrict__ vals_bf,
    ushort* __restrict__ msg_bf)
{
    const int bn = blockIdx.x, bm = blockIdx.y, b = blockIdx.z;
    const int n0 = bn * 64, m0 = bm * 64;
    const ushort* A = attn_bf + ((size_t)b << 18);
    const ushort* V = vals_bf + ((size_t)(b << 9)) * 256;
    const int t = threadIdx.x, w = t >> 6, l = t & 63;
    const int q = l >> 4, ln = l & 15;
    const int wm = (w >> 1) * 32, wn = (w & 1) * 32;

    f32x4 acc[2][2] = {};
    const int kmax = m0 + 64;
    for (int k0 = 0; k0 < kmax; k0 += 32) {
        bf16x8 a[2], bb[2];
#pragma unroll
        for (int mt = 0; mt < 2; ++mt)
            a[mt] = *(const bf16x8*)(A + (size_t)(m0 + wm + mt * 16 + ln) * S + k0 + q * 8);
#pragma unroll
        for (int nt = 0; nt < 2; ++nt) {
            const int n = n0 + wn + nt * 16 + ln;
            union { bf16x8 v; short s[8]; } u;
#pragma unroll
            for (int j = 0; j < 8; ++j)
                u.s[j] = (short)V[(size_t)(k0 + q * 8 + j) * 256 + n];
            bb[nt] = u.v;
        }
#pragma unroll
        for (int mt = 0; mt < 2; ++mt)
#pragma unroll
            for (int nt = 0; nt < 2; ++nt)
                acc[mt][nt] = __builtin_amdgcn_mfma_f32_16x16x32_bf16(a[mt], bb[nt], acc[mt][nt], 0, 0, 0);
    }
#pragma unroll
    for (int nt = 0; nt < 2; ++nt) {
        const int col = n0 + wn + nt * 16 + ln;
#pragma unroll
        for (int mt = 0; mt < 2; ++mt)
#pragma unroll
            for (int r = 0; r < 4; ++r) {
                const int row = (b << 9) + m0 + wm + mt * 16 + q * 4 + r;
                msg_bf[(size_t)row * 256 + col] = f2bf(acc[mt][nt][r]);
            }
    }
}

// ---------------------------------------------------------------------------
// Kernel 5: MFMA OUT + residual + bias + LayerNorm, fused.
// Block = 4 waves; wave w owns rows bm*64+w*16..+15, all 256 cols (16 n-tiles).
// Row stats via intra-quad shuffles (row lives in 16 lanes of one quad).
// ---------------------------------------------------------------------------
__global__ __launch_bounds__(256) void out_ln_mfma(
    const ushort* __restrict__ msg_bf, const ushort* __restrict__ Wot,
    const float* __restrict__ x, const float* __restrict__ bo,
    const float* __restrict__ gamma, const float* __restrict__ beta,
    float* __restrict__ out)
{
    const int bm = blockIdx.x;
    const int t = threadIdx.x, w = t >> 6, l = t & 63;
    const int q = l >> 4, ln = l & 15;
    const int rbase = bm * 64 + w * 16;

    f32x4 acc[16] = {};
    for (int k0 = 0; k0 < 256; k0 += 32) {
        bf16x8 a = *(const bf16x8*)(msg_bf + (size_t)(rbase + ln) * 256 + k0 + q * 8);
#pragma unroll
        for (int nt = 0; nt < 16; ++nt) {
            bf16x8 bb = *(const bf16x8*)(Wot + (size_t)(nt * 16 + ln) * 256 + k0 + q * 8);
            acc[nt] = __builtin_amdgcn_mfma_f32_16x16x32_bf16(a, bb, acc[nt], 0, 0, 0);
        }
    }

    float sum[4] = {}, sq[4] = {};
#pragma unroll
    for (int nt = 0; nt < 16; ++nt) {
        const int col = nt * 16 + ln;
        const float bov = bo[col];
#pragma unroll
        for (int r = 0; r < 4; ++r) {
            const int row = rbase + q * 4 + r;
            float v = acc[nt][r] + x[(size_t)row * 256 + col] + bov;
            acc[nt][r] = v;
            sum[r] += v;
            sq[r] += v * v;
        }
    }
#pragma unroll
    for (int r = 0; r < 4; ++r) {
#pragma unroll
        for (int off = 1; off < 16; off <<= 1) {
            sum[r] += __shfl_xor(sum[r], off, 64);
            sq[r]  += __shfl_xor(sq[r],  off, 64);
        }
    }
#pragma unroll
    for (int nt = 0; nt < 16; ++nt) {
        const int col = nt * 16 + ln;
        const float g = gamma[col], be = beta[col];
#pragma unroll
        for (int r = 0; r < 4; ++r) {
            const float mu = sum[r] * (1.f / 256.f);
            const float var = sq[r] * (1.f / 256.f) - mu * mu;
            const int row = rbase + q * 4 + r;
            out[(size_t)row * 256 + col] =
                (acc[nt][r] - mu) * rsqrtf(var + 1e-5f) * g + be;
        }
    }
}

// ---------------------------------------------------------------------------
extern "C" void kernel_launch(void* const* d_in, const int* in_sizes, int n_in,
                              void* d_out, int out_size, void* d_ws, size_t ws_size,
                              hipStream_t stream)
{
    (void)in_sizes; (void)n_in; (void)out_size; (void)ws_size;
    const float* x     = (const float*)d_in[0];
    const float* W1    = (const float*)d_in[1];
    const float* b1    = (const float*)d_in[2];
    const float* w2    = (const float*)d_in[3];
    const float* b2    = (const float*)d_in[4];
    const float* Wv    = (const float*)d_in[5];
    const float* bv    = (const float*)d_in[6];
    const float* Wo    = (const float*)d_in[7];
    const float* bo    = (const float*)d_in[8];
    const float* gamma = (const float*)d_in[9];
    const float* beta  = (const float*)d_in[10];
    float* out = (float*)d_out;

    // workspace layout in 256KB (64K-float) chunks
    float* ws = (float*)d_ws;
    const size_t CH = 64 * 1024;
    float*  hi      = ws;                       // 8 chunks (2048*256 f32)
    float*  hj      = ws + 8 * CH;              // 8
    float*  sc      = ws + 16 * CH;             // 16 (4*512*512 f32)
    ushort* xb      = (ushort*)(ws + 32 * CH);  // 4  (2048*256 bf16)
    ushort* WAt     = (ushort*)(ws + 36 * CH);  // 1
    ushort* WBt     = (ushort*)(ws + 37 * CH);  // 1
    ushort* Wvt     = (ushort*)(ws + 38 * CH);  // 1
    ushort* Wot     = (ushort*)(ws + 39 * CH);  // 1
    ushort* vals_bf = (ushort*)(ws + 40 * CH);  // 4
    ushort* attn_bf = (ushort*)(ws + 44 * CH);  // 8  (4*512*512 bf16)
    ushort* msg_bf  = (ushort*)(ws + 52 * CH);  // 4

    pack_all     <<<dim3(320),        256, 0, stream>>>(x, W1, Wv, Wo, xb, WAt, WBt, Wvt, Wot);
    gemm_qkv_mfma<<<dim3(12, 32),     256, 0, stream>>>(xb, WAt, WBt, Wvt, b1, bv, hi, hj, vals_bf);
    scores_tiled <<<dim3(16, 16, 4),  256, 0, stream>>>(hi, hj, w2, b2, sc);
    attn_norm    <<<dim3(M),          256, 0, stream>>>(sc, attn_bf);
    pv_mfma      <<<dim3(4, 8, 4),    256, 0, stream>>>(attn_bf, vals_bf, msg_bf);
    out_ln_mfma  <<<dim3(32),         256, 0, stream>>>(msg_bf, Wot, x, bo, gamma, beta, out);
}

// Round 4
// 141.039 us; speedup vs baseline: 1.4776x; 1.0800x over previous
//
#include <hip/hip_runtime.h>
#include <math.h>

#define D 256
#define S 512
#define M 2048  // 4 * 512

typedef __attribute__((ext_vector_type(8))) short bf16x8;
typedef __attribute__((ext_vector_type(4))) float f32x4;

__device__ inline ushort f2bf(float f) {
    union { float f; unsigned u; } v; v.f = f;
    unsigned r = v.u + 0x7FFFu + ((v.u >> 16) & 1u);   // RNE
    return (ushort)(r >> 16);
}

// ---------------------------------------------------------------------------
// Kernel 0: pack weights to bf16, transposed [n][k]:
//   WAt=Wa+Wc (T), WBt=Wb-Wc (T), Wvt=Wv^T, Wot=Wo^T.  64 blocks.
// ---------------------------------------------------------------------------
__global__ __launch_bounds__(256) void pack_w(
    const float* __restrict__ W1, const float* __restrict__ Wv,
    const float* __restrict__ Wo, ushort* __restrict__ WAt,
    ushort* __restrict__ WBt, ushort* __restrict__ Wvt, ushort* __restrict__ Wot)
{
    const int blk = blockIdx.x, t = threadIdx.x;
    const int mat = blk >> 4;
    const int a0 = ((blk >> 2) & 3) * 64;   // dst row block (n = src col)
    const int b0 = (blk & 3) * 64;          // dst col block (k = src row)
    __shared__ ushort lt[64][72];
    const int r = t >> 4;
    const int c = (t & 15) * 4;
#pragma unroll
    for (int p = 0; p < 4; ++p) {
        const int sr = b0 + p * 16 + r;
        float4 v;
        if (mat == 0) {
            float4 wa = *(const float4*)(W1 + (size_t)sr * 256 + a0 + c);
            float4 wc = *(const float4*)(W1 + (size_t)(512 + sr) * 256 + a0 + c);
            v = make_float4(wa.x + wc.x, wa.y + wc.y, wa.z + wc.z, wa.w + wc.w);
        } else if (mat == 1) {
            float4 wb = *(const float4*)(W1 + (size_t)(256 + sr) * 256 + a0 + c);
            float4 wc = *(const float4*)(W1 + (size_t)(512 + sr) * 256 + a0 + c);
            v = make_float4(wb.x - wc.x, wb.y - wc.y, wb.z - wc.z, wb.w - wc.w);
        } else if (mat == 2) {
            v = *(const float4*)(Wv + (size_t)sr * 256 + a0 + c);
        } else {
            v = *(const float4*)(Wo + (size_t)sr * 256 + a0 + c);
        }
        lt[p * 16 + r][c + 0] = f2bf(v.x);
        lt[p * 16 + r][c + 1] = f2bf(v.y);
        lt[p * 16 + r][c + 2] = f2bf(v.z);
        lt[p * 16 + r][c + 3] = f2bf(v.w);
    }
    __syncthreads();
    ushort* dst = (mat == 0) ? WAt : (mat == 1) ? WBt : (mat == 2) ? Wvt : Wot;
#pragma unroll
    for (int p = 0; p < 4; ++p) {
        const int dr = p * 16 + r;
        ushort4 o = make_ushort4(lt[c + 0][dr], lt[c + 1][dr],
                                 lt[c + 2][dr], lt[c + 3][dr]);
        *(ushort4*)(dst + (size_t)(a0 + dr) * 256 + b0 + c) = o;
    }
}

// ---------------------------------------------------------------------------
// Kernel 1: MFMA QKV.  x (f32, inline bf16 cvt) @ [WAt|WBt|Wvt]^T.
//   region 0 -> hi f32 (+b1), region 1 -> hj f32,
//   region 2 -> vals_t bf16 TRANSPOSED [b][e][j] via LDS (for pv B-frags).
// ---------------------------------------------------------------------------
__global__ __launch_bounds__(256) void gemm_qkv_mfma(
    const float* __restrict__ x, const ushort* __restrict__ WAt,
    const ushort* __restrict__ WBt, const ushort* __restrict__ Wvt,
    const float* __restrict__ b1, const float* __restrict__ bv,
    float* __restrict__ hi, float* __restrict__ hj, ushort* __restrict__ vals_t)
{
    const int bn = blockIdx.x, bm = blockIdx.y;
    const int n0 = bn * 64, m0 = bm * 64;
    const int region = n0 >> 8, c0 = n0 & 255;
    const ushort* Bt = (region == 0) ? WAt : (region == 1) ? WBt : Wvt;
    const int t = threadIdx.x, w = t >> 6, l = t & 63;
    const int q = l >> 4, ln = l & 15;
    const int wm = (w >> 1) * 32, wn = (w & 1) * 32;

    __shared__ ushort T[64][72];   // used only by region-2 blocks

    f32x4 acc[2][2] = {};
    for (int k0 = 0; k0 < 256; k0 += 32) {
        union { bf16x8 v; ushort s[8]; } a[2];
        bf16x8 b[2];
#pragma unroll
        for (int mt = 0; mt < 2; ++mt) {
            const float* xr = x + (size_t)(m0 + wm + mt * 16 + ln) * 256 + k0 + q * 8;
            float4 u0 = *(const float4*)xr;
            float4 u1 = *(const float4*)(xr + 4);
            a[mt].s[0] = f2bf(u0.x); a[mt].s[1] = f2bf(u0.y);
            a[mt].s[2] = f2bf(u0.z); a[mt].s[3] = f2bf(u0.w);
            a[mt].s[4] = f2bf(u1.x); a[mt].s[5] = f2bf(u1.y);
            a[mt].s[6] = f2bf(u1.z); a[mt].s[7] = f2bf(u1.w);
        }
#pragma unroll
        for (int nt = 0; nt < 2; ++nt)
            b[nt] = *(const bf16x8*)(Bt + (size_t)(c0 + wn + nt * 16 + ln) * 256 + k0 + q * 8);
#pragma unroll
        for (int mt = 0; mt < 2; ++mt)
#pragma unroll
            for (int nt = 0; nt < 2; ++nt)
                acc[mt][nt] = __builtin_amdgcn_mfma_f32_16x16x32_bf16(a[mt].v, b[nt], acc[mt][nt], 0, 0, 0);
    }

    if (region < 2) {
        float* dst = (region == 0) ? hi : hj;
#pragma unroll
        for (int nt = 0; nt < 2; ++nt) {
            const int col = c0 + wn + nt * 16 + ln;
            const float bias = (region == 0) ? b1[col] : 0.f;
#pragma unroll
            for (int mt = 0; mt < 2; ++mt)
#pragma unroll
                for (int r = 0; r < 4; ++r) {
                    const int row = m0 + wm + mt * 16 + q * 4 + r;
                    dst[(size_t)row * 256 + col] = acc[mt][nt][r] + bias;
                }
        }
    } else {
        // stage bias-added bf16 into T[col_local][row_local], then store transposed
#pragma unroll
        for (int nt = 0; nt < 2; ++nt) {
            const int cl = wn + nt * 16 + ln;
            const float bias = bv[c0 + cl];
#pragma unroll
            for (int mt = 0; mt < 2; ++mt)
#pragma unroll
                for (int r = 0; r < 4; ++r)
                    T[cl][wm + mt * 16 + q * 4 + r] = f2bf(acc[mt][nt][r] + bias);
        }
        __syncthreads();
        const int bb = m0 >> 9, jloc = m0 & 511;
#pragma unroll
        for (int p = 0; p < 2; ++p) {
            const int idx = p * 256 + t;
            const int e_l = idx & 63, jc = (idx >> 6) * 8;
            *(uint4*)(vals_t + ((size_t)(bb * 256 + c0 + e_l)) * 512 + jloc + jc) =
                *(const uint4*)&T[e_l][jc];
        }
    }
}

// ---------------------------------------------------------------------------
// Kernel 2: scores, 64i x 32j tiles.  Thread owns 4i x 2j.
//   His: LDS transpose [h][i] (2-way reads, free).  hj rows held in REGISTERS
//   (per-thread j fixed; loads broadcast within 16-lane groups).
//   Raw scores to sc (b2 omitted: softmax shift-invariant).
// ---------------------------------------------------------------------------
__global__ __launch_bounds__(256) void scores64(
    const float* __restrict__ hi, const float* __restrict__ hj,
    const float* __restrict__ w2, float* __restrict__ sc)
{
    const int jt = blockIdx.x, it = blockIdx.y, bb = blockIdx.z;
    if (jt > 2 * it + 1) return;
    const int i0 = it * 64, j0 = jt * 32;
    const int t = threadIdx.x, w = t >> 6, l = t & 63;
    const int q = l >> 4, ln = l & 15;

    __shared__ __align__(16) float His[32][64];   // [h][i]
    __shared__ __align__(16) float Sst[64][36];   // output staging
    __shared__ float w2s[256];
    if (t < 64) *(float4*)&w2s[t * 4] = *(const float4*)(w2 + t * 4);

    const int si = t & 63, sh = (t >> 6) * 8;
    const float* hisrc = hi + (size_t)((bb << 9) + i0 + si) * 256 + sh;
    const int jrow = w * 8 + q * 2;
    const float* hj0 = hj + (size_t)((bb << 9) + j0 + jrow) * 256;
    const float* hj1 = hj0 + 256;

    float acc00 = 0.f, acc01 = 0.f, acc10 = 0.f, acc11 = 0.f;
    float acc20 = 0.f, acc21 = 0.f, acc30 = 0.f, acc31 = 0.f;

    for (int hc = 0; hc < 256; hc += 32) {
        float4 a0 = *(const float4*)(hisrc + hc);
        float4 a1 = *(const float4*)(hisrc + hc + 4);
        float e0[32], e1[32];
#pragma unroll
        for (int c = 0; c < 8; ++c) {
            *(float4*)&e0[c * 4] = *(const float4*)(hj0 + hc + c * 4);
            *(float4*)&e1[c * 4] = *(const float4*)(hj1 + hc + c * 4);
        }
        __syncthreads();   // protect previous chunk's His reads
        His[sh + 0][si] = a0.x; His[sh + 1][si] = a0.y;
        His[sh + 2][si] = a0.z; His[sh + 3][si] = a0.w;
        His[sh + 4][si] = a1.x; His[sh + 5][si] = a1.y;
        His[sh + 6][si] = a1.z; His[sh + 7][si] = a1.w;
        __syncthreads();
#pragma unroll
        for (int h = 0; h < 32; ++h) {
            float4 a = *(const float4*)&His[h][ln * 4];
            const float wv = w2s[hc + h];
            const float f0 = e0[h], f1 = e1[h];
            acc00 += fmaxf(a.x + f0, 0.f) * wv;
            acc01 += fmaxf(a.x + f1, 0.f) * wv;
            acc10 += fmaxf(a.y + f0, 0.f) * wv;
            acc11 += fmaxf(a.y + f1, 0.f) * wv;
            acc20 += fmaxf(a.z + f0, 0.f) * wv;
            acc21 += fmaxf(a.z + f1, 0.f) * wv;
            acc30 += fmaxf(a.w + f0, 0.f) * wv;
            acc31 += fmaxf(a.w + f1, 0.f) * wv;
        }
    }

    Sst[ln * 4 + 0][jrow] = acc00;  Sst[ln * 4 + 0][jrow + 1] = acc01;
    Sst[ln * 4 + 1][jrow] = acc10;  Sst[ln * 4 + 1][jrow + 1] = acc11;
    Sst[ln * 4 + 2][jrow] = acc20;  Sst[ln * 4 + 2][jrow + 1] = acc21;
    Sst[ln * 4 + 3][jrow] = acc30;  Sst[ln * 4 + 3][jrow + 1] = acc31;
    __syncthreads();
    const int i_l = t >> 2, jc = (t & 3) * 8;
    float* dst = sc + ((size_t)bb << 18) + (size_t)(i0 + i_l) * 512 + j0 + jc;
    *(float4*)dst       = *(const float4*)&Sst[i_l][jc];
    *(float4*)(dst + 4) = *(const float4*)&Sst[i_l][jc + 4];
}

// ---------------------------------------------------------------------------
// Kernel 3: softmax over j<i -> attn_bf (bf16, zero-filled j>=i and row 0).
// ---------------------------------------------------------------------------
__global__ __launch_bounds__(256) void attn_norm(
    const float* __restrict__ sc, ushort* __restrict__ attn_bf)
{
    const int row = blockIdx.x;
    const int b = row >> 9, i = row & 511;
    const int t = threadIdx.x, wave = t >> 6, lane = t & 63;
    ushort* arow = attn_bf + ((size_t)(b << 9) + i) * S;

    if (i == 0) { arow[t] = 0; arow[t + 256] = 0; return; }

    const float* srow = sc + ((size_t)b << 18) + (size_t)i * S;
    __shared__ float s[S];
    __shared__ float red[8];

    float mloc = -3.0e38f;
    for (int j = t; j < i; j += 256) { float v = srow[j]; s[j] = v; mloc = fmaxf(mloc, v); }
#pragma unroll
    for (int off = 32; off; off >>= 1) mloc = fmaxf(mloc, __shfl_xor(mloc, off, 64));
    if (lane == 0) red[wave] = mloc;
    __syncthreads();
    const float mx = fmaxf(fmaxf(red[0], red[1]), fmaxf(red[2], red[3]));

    float sloc = 0.f;
    for (int j = t; j < i; j += 256) {
        float e = __expf(s[j] - mx);
        s[j] = e;
        sloc += e;
    }
#pragma unroll
    for (int off = 32; off; off >>= 1) sloc += __shfl_xor(sloc, off, 64);
    if (lane == 0) red[4 + wave] = sloc;
    __syncthreads();
    const float inv = 1.f / (red[4] + red[5] + red[6] + red[7]);

    for (int j = t; j < S; j += 256)
        arow[j] = (j < i) ? f2bf(s[j] * inv) : (ushort)0;
}

// ---------------------------------------------------------------------------
// Kernel 4: MFMA PV.  msg = attn @ vals, causal K-truncation.
//   A-frags contiguous from attn_bf; B-frags contiguous from vals_t [e][j].
// ---------------------------------------------------------------------------
__global__ __launch_bounds__(256) void pv_mfma(
    const ushort* __restrict__ attn_bf, const ushort* __restrict__ vals_t,
    ushort* __restrict__ msg_bf)
{
    const int bn = blockIdx.x, bm = blockIdx.y, b = blockIdx.z;
    const int n0 = bn * 64, m0 = bm * 64;
    const ushort* A = attn_bf + ((size_t)b << 18);
    const ushort* V = vals_t + (size_t)(b * 256) * 512;
    const int t = threadIdx.x, w = t >> 6, l = t & 63;
    const int q = l >> 4, ln = l & 15;
    const int wm = (w >> 1) * 32, wn = (w & 1) * 32;

    f32x4 acc[2][2] = {};
    const int kmax = m0 + 64;
    for (int k0 = 0; k0 < kmax; k0 += 32) {
        bf16x8 a[2], bb[2];
#pragma unroll
        for (int mt = 0; mt < 2; ++mt)
            a[mt] = *(const bf16x8*)(A + (size_t)(m0 + wm + mt * 16 + ln) * S + k0 + q * 8);
#pragma unroll
        for (int nt = 0; nt < 2; ++nt)
            bb[nt] = *(const bf16x8*)(V + (size_t)(n0 + wn + nt * 16 + ln) * 512 + k0 + q * 8);
#pragma unroll
        for (int mt = 0; mt < 2; ++mt)
#pragma unroll
            for (int nt = 0; nt < 2; ++nt)
                acc[mt][nt] = __builtin_amdgcn_mfma_f32_16x16x32_bf16(a[mt], bb[nt], acc[mt][nt], 0, 0, 0);
    }
#pragma unroll
    for (int nt = 0; nt < 2; ++nt) {
        const int col = n0 + wn + nt * 16 + ln;
#pragma unroll
        for (int mt = 0; mt < 2; ++mt)
#pragma unroll
            for (int r = 0; r < 4; ++r) {
                const int row = (b << 9) + m0 + wm + mt * 16 + q * 4 + r;
                msg_bf[(size_t)row * 256 + col] = f2bf(acc[mt][nt][r]);
            }
    }
}

// ---------------------------------------------------------------------------
// Kernel 5: MFMA OUT + residual + bias + LayerNorm.  128 blocks x 16 rows.
//   Wave w covers cols w*64..w*64+63; cross-wave row stats via LDS.
// ---------------------------------------------------------------------------
__global__ __launch_bounds__(256) void out_ln_mfma(
    const ushort* __restrict__ msg_bf, const ushort* __restrict__ Wot,
    const float* __restrict__ x, const float* __restrict__ bo,
    const float* __restrict__ gamma, const float* __restrict__ beta,
    float* __restrict__ out)
{
    const int r0 = blockIdx.x * 16;
    const int t = threadIdx.x, w = t >> 6, l = t & 63;
    const int q = l >> 4, ln = l & 15;

    __shared__ float redS[16][4], redQ[16][4];

    f32x4 acc[4] = {};
    for (int k0 = 0; k0 < 256; k0 += 32) {
        bf16x8 a = *(const bf16x8*)(msg_bf + (size_t)(r0 + ln) * 256 + k0 + q * 8);
#pragma unroll
        for (int nt = 0; nt < 4; ++nt) {
            bf16x8 bb = *(const bf16x8*)(Wot + (size_t)(w * 64 + nt * 16 + ln) * 256 + k0 + q * 8);
            acc[nt] = __builtin_amdgcn_mfma_f32_16x16x32_bf16(a, bb, acc[nt], 0, 0, 0);
        }
    }

    float sum[4] = {}, sq[4] = {};
#pragma unroll
    for (int nt = 0; nt < 4; ++nt) {
        const int col = w * 64 + nt * 16 + ln;
        const float bov = bo[col];
#pragma unroll
        for (int r = 0; r < 4; ++r) {
            const int row = r0 + q * 4 + r;
            float v = acc[nt][r] + x[(size_t)row * 256 + col] + bov;
            acc[nt][r] = v;
            sum[r] += v;
            sq[r] += v * v;
        }
    }
#pragma unroll
    for (int r = 0; r < 4; ++r) {
#pragma unroll
        for (int off = 1; off < 16; off <<= 1) {
            sum[r] += __shfl_xor(sum[r], off, 64);
            sq[r]  += __shfl_xor(sq[r],  off, 64);
        }
    }
    if (ln == 0) {
#pragma unroll
        for (int r = 0; r < 4; ++r) {
            redS[q * 4 + r][w] = sum[r];
            redQ[q * 4 + r][w] = sq[r];
        }
    }
    __syncthreads();
#pragma unroll
    for (int nt = 0; nt < 4; ++nt) {
        const int col = w * 64 + nt * 16 + ln;
        const float g = gamma[col], be = beta[col];
#pragma unroll
        for (int r = 0; r < 4; ++r) {
            const int rl = q * 4 + r;
            const float ts = redS[rl][0] + redS[rl][1] + redS[rl][2] + redS[rl][3];
            const float tq = redQ[rl][0] + redQ[rl][1] + redQ[rl][2] + redQ[rl][3];
            const float mu = ts * (1.f / 256.f);
            const float var = tq * (1.f / 256.f) - mu * mu;
            out[(size_t)(r0 + rl) * 256 + col] =
                (acc[nt][r] - mu) * rsqrtf(var + 1e-5f) * g + be;
        }
    }
}

// ---------------------------------------------------------------------------
extern "C" void kernel_launch(void* const* d_in, const int* in_sizes, int n_in,
                              void* d_out, int out_size, void* d_ws, size_t ws_size,
                              hipStream_t stream)
{
    (void)in_sizes; (void)n_in; (void)out_size; (void)ws_size;
    const float* x     = (const float*)d_in[0];
    const float* W1    = (const float*)d_in[1];
    const float* b1    = (const float*)d_in[2];
    const float* w2    = (const float*)d_in[3];
    const float* Wv    = (const float*)d_in[5];
    const float* bv    = (const float*)d_in[6];
    const float* Wo    = (const float*)d_in[7];
    const float* bo    = (const float*)d_in[8];
    const float* gamma = (const float*)d_in[9];
    const float* beta  = (const float*)d_in[10];
    float* out = (float*)d_out;

    // workspace layout in 256KB (64K-float) chunks
    float* ws = (float*)d_ws;
    const size_t CH = 64 * 1024;
    float*  hi      = ws;                       // 8 chunks (2048*256 f32)
    float*  hj      = ws + 8 * CH;              // 8
    float*  sc      = ws + 16 * CH;             // 16 (4*512*512 f32)
    ushort* WAt     = (ushort*)(ws + 32 * CH);  // 1
    ushort* WBt     = (ushort*)(ws + 33 * CH);  // 1
    ushort* Wvt     = (ushort*)(ws + 34 * CH);  // 1
    ushort* Wot     = (ushort*)(ws + 35 * CH);  // 1
    ushort* vals_t  = (ushort*)(ws + 36 * CH);  // 4  (4*256*512 bf16, [b][e][j])
    ushort* attn_bf = (ushort*)(ws + 40 * CH);  // 8  (4*512*512 bf16)
    ushort* msg_bf  = (ushort*)(ws + 48 * CH);  // 4

    pack_w       <<<dim3(64),        256, 0, stream>>>(W1, Wv, Wo, WAt, WBt, Wvt, Wot);
    gemm_qkv_mfma<<<dim3(12, 32),    256, 0, stream>>>(x, WAt, WBt, Wvt, b1, bv, hi, hj, vals_t);
    scores64     <<<dim3(16, 8, 4),  256, 0, stream>>>(hi, hj, w2, sc);
    attn_norm    <<<dim3(M),         256, 0, stream>>>(sc, attn_bf);
    pv_mfma      <<<dim3(4, 8, 4),   256, 0, stream>>>(attn_bf, vals_t, msg_bf);
    out_ln_mfma  <<<dim3(128),       256, 0, stream>>>(msg_bf, Wot, x, bo, gamma, beta, out);
}